// Round 7
// baseline (423.799 us; speedup 1.0000x reference)
//
#include <hip/hip_runtime.h>
#include <hip/hip_bf16.h>
#include <cstdint>
#include <cstddef>

namespace {

constexpr int kB = 512, kT = 32, kH = 768, kF = 3072, kE = 3;
constexpr int kMaxTiles = 132;   // sum 2*ceil(cnt_e/8) <= 132 (pairs, expert-uniform)
constexpr int kMaxChunk = 132;
constexpr int kHbufTile = 128 * kF;   // 393216 elts per 128-row tile
constexpr int kXconvB = kT * kH;      // 24576 elts per batch

typedef __attribute__((ext_vector_type(8))) short short8;
typedef __attribute__((ext_vector_type(4))) float f32x4;

__device__ __forceinline__ void gld_lds16(const void* g, void* l) {
  __builtin_amdgcn_global_load_lds(
      (const __attribute__((address_space(1))) void*)g,
      (__attribute__((address_space(3))) void*)l, 16, 0, 0);
}

__device__ __forceinline__ float bf2f(__hip_bfloat16 v) { return __bfloat162float(v); }
__device__ __forceinline__ float bfu(unsigned short u) {
  return __uint_as_float(((unsigned)u) << 16);
}
__device__ __forceinline__ unsigned short f2bfb(float f) {
  __hip_bfloat16 h = __float2bfloat16(f);
  return *reinterpret_cast<unsigned short*>(&h);
}

// exact-grade gelu: Abramowitz-Stegun 7.1.26 erf, |err| <= 1.5e-7
__device__ __forceinline__ float gelu_f(float v) {
  float av = fabsf(v);
  float z = av * 0.70710678118654752f;
  float t = __builtin_amdgcn_rcpf(fmaf(0.3275911f, z, 1.0f));
  float p = fmaf(fmaf(fmaf(fmaf(1.061405429f, t, -1.453152027f), t, 1.421413741f),
                      t, -0.284496736f), t, 0.254829592f) * t;
  float er = fmaf(-p, __expf(-z * z), 1.0f);   // erf(z), z >= 0
  return 0.5f * v + 0.5f * av * er;
}

// ---------------- merged prep: [0,kB) route+convert blocks; [kB,kB+3456) transpose blocks ----
// prep path: sniff + route + repack x -> xconv; last-ticket block packs PAIR-uniform tiles.
// transpose path: z<3: W1 [e][H][F] -> w1t [e][F][H]; z>=3: W2 [e][F][H] -> w2t [e][H][F]
__global__ __launch_bounds__(256)
void k_prep(const void* __restrict__ xv, const void* __restrict__ Wgv,
            const void* __restrict__ w1src, const void* __restrict__ w2src,
            float* __restrict__ wsel, int* __restrict__ cntTk,
            int* __restrict__ lists, int* __restrict__ tileExpert,
            int* __restrict__ tileBatch, int* __restrict__ numTiles,
            __hip_bfloat16* __restrict__ xconv,
            __hip_bfloat16* __restrict__ w1dst, __hip_bfloat16* __restrict__ w2dst) {
  __shared__ __align__(16) char smem[52992];
  __shared__ int ish[6];
  int tid = threadIdx.x;
  if (blockIdx.x < (unsigned)kB) {
    // ---------------- prep path ----------------
    auto xs = (unsigned short (*)[772])smem;                 // 32 x 772 ushort
    float (*red)[256] = (float (*)[256])(smem + 49408);      // 3 x 256 f32
    int b = blockIdx.x;
    if (tid == 0) { ish[0] = 0; ish[1] = 0; }
    __syncthreads();
    {
      const unsigned short* xw = (const unsigned short*)xv;
      const unsigned short* gw = (const unsigned short*)Wgv;
      int lx = 0, lg = 0;
#pragma unroll
      for (int i = 0; i < 16; ++i) lx += (((xw[tid + 256 * i] >> 7) & 0xFF) >= 0xC0);
#pragma unroll
      for (int i = 0; i < 8; ++i) lg += (((gw[tid + 256 * i] >> 7) & 0xFF) >= 0xC0);
      atomicAdd(&ish[0], lx);
      atomicAdd(&ish[1], lg);
    }
    __syncthreads();
    bool fx = (ish[0] > 64), fg = (ish[1] > 32);
    float a0 = 0.f, a1 = 0.f, a2 = 0.f;
    if (tid < 192) {
      float m0 = 0.f, m1 = 0.f, m2 = 0.f, m3 = 0.f;
      if (fx) {
        const float4* xr = (const float4*)((const float*)xv + (size_t)b * kT * kH) + tid;
#pragma unroll 8
        for (int t = 0; t < kT; ++t) {
          float4 u = xr[t * 192];
          m0 += u.x; m1 += u.y; m2 += u.z; m3 += u.w;
          ushort4 v;
          v.x = f2bfb(u.x); v.y = f2bfb(u.y); v.z = f2bfb(u.z); v.w = f2bfb(u.w);
          *(ushort4*)&xs[t][tid * 4] = v;
        }
      } else {
        const ushort4* xr = (const ushort4*)((const unsigned short*)xv + (size_t)b * kT * kH) + tid;
#pragma unroll 8
        for (int t = 0; t < kT; ++t) {
          ushort4 u = xr[t * 192];
          m0 += bfu(u.x); m1 += bfu(u.y); m2 += bfu(u.z); m3 += bfu(u.w);
          *(ushort4*)&xs[t][tid * 4] = u;
        }
      }
      const float inv = 1.f / kT;
      m0 *= inv; m1 *= inv; m2 *= inv; m3 *= inv;
#pragma unroll
      for (int e = 0; e < kE; ++e) {
        float w0, w1v, w2v, w3;
        int base = e * kH + tid * 4;
        if (fg) {
          float4 u = *(const float4*)((const float*)Wgv + base);
          w0 = u.x; w1v = u.y; w2v = u.z; w3 = u.w;
        } else {
          ushort4 u = *(const ushort4*)((const unsigned short*)Wgv + base);
          w0 = bfu(u.x); w1v = bfu(u.y); w2v = bfu(u.z); w3 = bfu(u.w);
        }
        float d = m0 * w0 + m1 * w1v + m2 * w2v + m3 * w3;
        if (e == 0) a0 = d; else if (e == 1) a1 = d; else a2 = d;
      }
    }
    red[0][tid] = a0; red[1][tid] = a1; red[2][tid] = a2;
    __syncthreads();
    for (int s2 = 128; s2 > 0; s2 >>= 1) {
      if (tid < s2) {
        red[0][tid] += red[0][tid + s2];
        red[1][tid] += red[1][tid + s2];
        red[2][tid] += red[2][tid + s2];
      }
      __syncthreads();
    }
    if (tid == 0) {
      float l0 = red[0][0], l1 = red[1][0], l2 = red[2][0];
      int am = 0; float mx = l0;
      if (l1 > mx) { mx = l1; am = 1; }
      if (l2 > mx) { mx = l2; am = 2; }
      float e0 = expf(l0 - mx), e1 = expf(l1 - mx), e2 = expf(l2 - mx);
      float inv = 1.f / (e0 + e1 + e2);
      float sc = (am == 0 ? e0 : (am == 1 ? e1 : e2)) * inv;
      wsel[b] = sc;
      int pos = atomicAdd(&cntTk[am], 1);
      lists[am * kB + pos] = b;
      __threadfence();                       // release
      int tk = atomicAdd(&cntTk[3], 1);
      ish[2] = (tk == kB - 1) ? 1 : 0;
    }
    __syncthreads();
    // repack xs -> xconv[b] (ffn1 A-staging order)
    unsigned short* dst = (unsigned short*)xconv + (size_t)b * kXconvB;
#pragma unroll
    for (int i = 0; i < 12; ++i) {
      int g = i * 256 + tid;               // 0..3071
      int t32 = g >> 7, r = g & 127, mm = r >> 2, qp = r & 3;
      int col = t32 * 32 + (qp ^ ((mm >> 1) & 3)) * 8;
      ushort4 lo = *(const ushort4*)&xs[mm][col];
      ushort4 hi = *(const ushort4*)&xs[mm][col + 4];
      short8 v;
      v[0] = lo.x; v[1] = lo.y; v[2] = lo.z; v[3] = lo.w;
      v[4] = hi.x; v[5] = hi.y; v[6] = hi.z; v[7] = hi.w;
      *(short8*)(dst + g * 8) = v;
    }
    if (ish[2]) {                          // last block: parallel PAIR-uniform packing
      __threadfence();                     // acquire
      if (tid < 3) ish[3 + tid] = cntTk[tid];
      __syncthreads();
      int c0 = ish[3], c1 = ish[4], c2 = ish[5];
      int t0 = ((c0 + 7) & ~7) >> 2;       // 2*ceil(c/8) -> even, pairs expert-uniform
      int t1 = ((c1 + 7) & ~7) >> 2;
      int t2 = ((c2 + 7) & ~7) >> 2;
      int total = t0 + t1 + t2;
      if (tid == 0) *numTiles = total;
      for (int t = tid; t < kMaxTiles; t += 256) {
        int e = 0, base = 0, cc = 0;
        bool pad = false;
        if (t < t0) { e = 0; base = t; cc = c0; }
        else if (t < t0 + t1) { e = 1; base = t - t0; cc = c1; }
        else if (t < total) { e = 2; base = t - t0 - t1; cc = c2; }
        else pad = true;
        if (pad) {
          tileExpert[t] = 0;
          for (int s = 0; s < 4; ++s) tileBatch[t * 4 + s] = -1;
        } else {
          tileExpert[t] = e;
          for (int s = 0; s < 4; ++s) {
            int i = base * 4 + s;
            tileBatch[t * 4 + s] = (i < cc) ? lists[e * kB + i] : -1;
          }
        }
      }
    }
  } else {
    // ---------------- transpose path ----------------
    auto tsh = (unsigned short (*)[73])smem;                 // 64 x 73 ushort
    int bid = blockIdx.x - kB;
    int z = bid / 576, bx = bid - z * 576;
    bool isW1 = (z < 3);
    int e = isW1 ? z : z - 3;
    if (tid == 0) ish[0] = 0;
    __syncthreads();
    {
      const unsigned short* hw = (const unsigned short*)(isW1 ? w1src : w2src);
      int local = 0;
#pragma unroll
      for (int i = 0; i < 16; ++i)
        local += (((hw[tid + 256 * i] >> 7) & 0xFF) >= 0xC0);
      atomicAdd(&ish[0], local);
    }
    __syncthreads();
    bool f32 = (ish[0] > 64);
    const float* sf = (const float*)(isW1 ? w1src : w2src);
    const unsigned short* sb = (const unsigned short*)(isW1 ? w1src : w2src);
    unsigned short* dst = (unsigned short*)(isW1 ? w1dst : w2dst);
    int K = isW1 ? kH : kF, N = isW1 ? kF : kH;
    int ntx = N / 64;
    int n0 = (bx % ntx) * 64, k0 = (bx / ntx) * 64;
    size_t eoff = (size_t)e * K * N;
    int tr = tid >> 4;
    int tc4 = (tid & 15) * 4;
#pragma unroll
    for (int i = 0; i < 4; ++i) {
      int r = tr + 16 * i;
      size_t idx = eoff + (size_t)(k0 + r) * N + n0 + tc4;
      if (f32) {
        float4 u = *(const float4*)(sf + idx);
        tsh[r][tc4] = f2bfb(u.x); tsh[r][tc4 + 1] = f2bfb(u.y);
        tsh[r][tc4 + 2] = f2bfb(u.z); tsh[r][tc4 + 3] = f2bfb(u.w);
      } else {
        ushort4 u = *(const ushort4*)(sb + idx);
        tsh[r][tc4] = u.x; tsh[r][tc4 + 1] = u.y; tsh[r][tc4 + 2] = u.z; tsh[r][tc4 + 3] = u.w;
      }
    }
    __syncthreads();
#pragma unroll
    for (int i = 0; i < 4; ++i) {
      int rn = tr + 16 * i;
      ushort4 v;
      v.x = tsh[tc4][rn]; v.y = tsh[tc4 + 1][rn];
      v.z = tsh[tc4 + 2][rn]; v.w = tsh[tc4 + 3][rn];
      *(ushort4*)(dst + eoff + (size_t)(n0 + rn) * K + k0 + tc4) = v;
    }
  }
}

// ---------------- GEMM1: 256x256 pair-tile, BK=64, 4 fine phases/K-tile (m201-style) --------
// 512 thr = 8 waves (wr 2 x wc 4), per-wave 128x64 output, acc[8][4].
// LDS 128 KiB = 2 slots x {A 256x64 | B 256x64}. Per K-tile t, 4 phases, each:
// {<=8 ds_read_b128 | 2 gld_lds of tile t+1 chunk} barrier; lgkmcnt(0); 16 MFMA; barrier.
// Counted vmcnt(4) twice per K-tile (never cold-drains in steady state).
__global__ __launch_bounds__(512, 2)
void k_ffn1(const __hip_bfloat16* __restrict__ xconv,
            const __hip_bfloat16* __restrict__ w1t,  // [E][F][H] bf16
            const __hip_bfloat16* __restrict__ b1,
            const int* __restrict__ tileExpert,
            const int* __restrict__ tileBatch,
            const int* __restrict__ numTiles,
            int tileOff, int chunk,
            __hip_bfloat16* __restrict__ hbuf) {
  extern __shared__ __align__(16) short lds[];     // 65536 shorts
  int nblk = (chunk >> 1) * 12;
  int lid = blockIdx.x * gridDim.y + blockIdx.y;   // XCD-chunked
  if (lid >= nblk) return;
  int lpair = lid / 12;
  int nb = lid - lpair * 12;
  int nbase = nb * 256;                            // f-range
  int tile0 = tileOff + 2 * lpair;
  if (tile0 >= *numTiles) return;
  int e = tileExpert[tile0];
  int tid = threadIdx.x;
  int lane = tid & 63, wid = tid >> 6;
  int wr = wid >> 2, wc = wid & 3;                 // 2 row-waves x 4 col-waves
  int lane16 = lane & 15, qf = lane >> 4;
  int qx = (qf ^ ((lane16 >> 1) & 3)) * 8;
  int tid8 = tid * 8;

  // staging sources (per-lane; batches via pair slots 0..7)
  int b0v = tileBatch[tile0 * 4];                  // always valid
  int bA0 = tileBatch[tile0 * 4 + (tid >> 7)];
  int bA1 = tileBatch[tile0 * 4 + 4 + (tid >> 7)];
  if (bA0 < 0) bA0 = b0v;
  if (bA1 < 0) bA1 = b0v;
  int aoffc = (((tid >> 2) & 31) * 4 + (tid & 3)) * 8;
  const __hip_bfloat16* pA0 = xconv + (size_t)bA0 * kXconvB + aoffc;
  const __hip_bfloat16* pA1 = xconv + (size_t)bA1 * kXconvB + aoffc;
  const __hip_bfloat16* w1e = w1t + (size_t)e * kF * kH;
  int q8 = ((tid & 3) ^ ((tid >> 3) & 3)) * 8;
  const __hip_bfloat16* pB0 = w1e + (size_t)(nbase + (tid >> 2)) * kH + q8;
  const __hip_bfloat16* pB1 = w1e + (size_t)(nbase + 128 + (tid >> 2)) * kH + q8;
  const int baseA = (wr * 128 + lane16) * 32 + qx;
  const int baseB = 16384 + (wc * 64 + lane16) * 32 + qx;

  f32x4 acc[8][4];
#pragma unroll
  for (int r = 0; r < 8; ++r)
#pragma unroll
    for (int c = 0; c < 4; ++c) acc[r][c] = (f32x4)0.f;

  // prologue: stage tile 0 chunks in order A-kk0, B-kk0, A-kk1, B-kk1 into slot 0
  gld_lds16(pA0, &lds[tid8]);
  gld_lds16(pA1, &lds[4096 + tid8]);
  gld_lds16(pB0, &lds[16384 + tid8]);
  gld_lds16(pB1, &lds[16384 + 4096 + tid8]);
  gld_lds16(pA0 + 1024, &lds[8192 + tid8]);
  gld_lds16(pA1 + 1024, &lds[8192 + 4096 + tid8]);
  gld_lds16(pB0 + 32, &lds[16384 + 8192 + tid8]);
  gld_lds16(pB1 + 32, &lds[16384 + 8192 + 4096 + tid8]);
  asm volatile("s_waitcnt vmcnt(4)" ::: "memory");   // A-kk0,B-kk0 landed
  __builtin_amdgcn_s_barrier();

#define MF(r_, c_, A_, B_) \
  acc[r_][c_] = __builtin_amdgcn_mfma_f32_16x16x32_bf16(A_, B_, acc[r_][c_], 0, 0, 0)
#define MF16(RB)                                                \
  MF(RB + 0, 0, a0, b0); MF(RB + 0, 1, a0, b1);                 \
  MF(RB + 0, 2, a0, b2); MF(RB + 0, 3, a0, b3);                 \
  MF(RB + 1, 0, a1, b0); MF(RB + 1, 1, a1, b1);                 \
  MF(RB + 1, 2, a1, b2); MF(RB + 1, 3, a1, b3);                 \
  MF(RB + 2, 0, a2, b0); MF(RB + 2, 1, a2, b1);                 \
  MF(RB + 2, 2, a2, b2); MF(RB + 2, 3, a2, b3);                 \
  MF(RB + 3, 0, a3, b0); MF(RB + 3, 1, a3, b1);                 \
  MF(RB + 3, 2, a3, b2); MF(RB + 3, 3, a3, b3)
#define LGKM_FENCE                                              \
  asm volatile("s_waitcnt lgkmcnt(0)" ::: "memory");            \
  __builtin_amdgcn_sched_barrier(0)

#pragma unroll 1
  for (int t = 0; t < 12; ++t) {
    const short* cur = &lds[(t & 1) * 32768];
    short* nxt = &lds[((t + 1) & 1) * 32768];
    const bool hn = (t + 1) < 12;
    const int tA = (t + 1) * 2048;
    const int tB = (t + 1) * 64;
    short8 a0, a1, a2, a3, b0, b1, b2, b3;
    // ---- phase 0: kk0, acc rows 0-3; stage A-kk0[t+1]
    b0 = *(const short8*)&cur[baseB];
    b1 = *(const short8*)&cur[baseB + 512];
    b2 = *(const short8*)&cur[baseB + 1024];
    b3 = *(const short8*)&cur[baseB + 1536];
    a0 = *(const short8*)&cur[baseA];
    a1 = *(const short8*)&cur[baseA + 512];
    a2 = *(const short8*)&cur[baseA + 1024];
    a3 = *(const short8*)&cur[baseA + 1536];
    if (hn) {
      gld_lds16(pA0 + tA, nxt + tid8);
      gld_lds16(pA1 + tA, nxt + 4096 + tid8);
    }
    __builtin_amdgcn_s_barrier();
    LGKM_FENCE;
    __builtin_amdgcn_s_setprio(1);
    MF16(0);
    __builtin_amdgcn_s_setprio(0);
    __builtin_amdgcn_s_barrier();
    // ---- phase 1: kk0, acc rows 4-7; stage B-kk0[t+1]; vmcnt ensures kk1[t] landed
    a0 = *(const short8*)&cur[baseA + 2048];
    a1 = *(const short8*)&cur[baseA + 2560];
    a2 = *(const short8*)&cur[baseA + 3072];
    a3 = *(const short8*)&cur[baseA + 3584];
    if (hn) {
      gld_lds16(pB0 + tB, nxt + 16384 + tid8);
      gld_lds16(pB1 + tB, nxt + 16384 + 4096 + tid8);
      asm volatile("s_waitcnt vmcnt(4)" ::: "memory");
    } else {
      asm volatile("s_waitcnt vmcnt(0)" ::: "memory");
    }
    __builtin_amdgcn_s_barrier();
    LGKM_FENCE;
    __builtin_amdgcn_s_setprio(1);
    MF16(4);
    __builtin_amdgcn_s_setprio(0);
    __builtin_amdgcn_s_barrier();
    // ---- phase 2: kk1, acc rows 0-3; stage A-kk1[t+1]
    b0 = *(const short8*)&cur[8192 + baseB];
    b1 = *(const short8*)&cur[8192 + baseB + 512];
    b2 = *(const short8*)&cur[8192 + baseB + 1024];
    b3 = *(const short8*)&cur[8192 + baseB + 1536];
    a0 = *(const short8*)&cur[8192 + baseA];
    a1 = *(const short8*)&cur[8192 + baseA + 512];
    a2 = *(const short8*)&cur[8192 + baseA + 1024];
    a3 = *(const short8*)&cur[8192 + baseA + 1536];
    if (hn) {
      gld_lds16(pA0 + tA + 1024, nxt + 8192 + tid8);
      gld_lds16(pA1 + tA + 1024, nxt + 8192 + 4096 + tid8);
    }
    __builtin_amdgcn_s_barrier();
    LGKM_FENCE;
    __builtin_amdgcn_s_setprio(1);
    MF16(0);
    __builtin_amdgcn_s_setprio(0);
    __builtin_amdgcn_s_barrier();
    // ---- phase 3: kk1, acc rows 4-7; stage B-kk1[t+1]; vmcnt ensures kk0[t+1] landed
    a0 = *(const short8*)&cur[8192 + baseA + 2048];
    a1 = *(const short8*)&cur[8192 + baseA + 2560];
    a2 = *(const short8*)&cur[8192 + baseA + 3072];
    a3 = *(const short8*)&cur[8192 + baseA + 3584];
    if (hn) {
      gld_lds16(pB0 + tB + 32, nxt + 16384 + 8192 + tid8);
      gld_lds16(pB1 + tB + 32, nxt + 16384 + 8192 + 4096 + tid8);
      asm volatile("s_waitcnt vmcnt(4)" ::: "memory");
    }
    __builtin_amdgcn_s_barrier();
    LGKM_FENCE;
    __builtin_amdgcn_s_setprio(1);
    MF16(4);
    __builtin_amdgcn_s_setprio(0);
    __builtin_amdgcn_s_barrier();
  }
#undef MF
#undef MF16
#undef LGKM_FENCE

  // ---- epilogue: gelu(acc+bias) -> LDS bounce (hbuf-staged order, r5-proven pattern)
  int q4 = qf * 4;
#pragma unroll
  for (int c = 0; c < 4; ++c) {
    int nl = wc * 64 + c * 16 + lane16;            // 0..255 within block f-range
    float bias = bf2f(b1[e * kF + nbase + nl]);
    int lb = wr * 32768 + (nl >> 6) * 8192 + ((nl >> 5) & 1) * 4096 + (nl & 7);
    int qn = (nl >> 3) & 3;
#pragma unroll
    for (int r = 0; r < 8; ++r) {
#pragma unroll
      for (int g = 0; g < 4; ++g) {
        int m = r * 16 + q4 + g;                   // row within 128-row tile
        lds[lb + (m * 4 + (qn ^ ((m >> 1) & 3))) * 8] =
            (short)f2bfb(gelu_f(acc[r][c][g] + bias));
      }
    }
  }
  __syncthreads();
  unsigned short* h0 = (unsigned short*)hbuf + (size_t)(2 * lpair) * kHbufTile +
                       (size_t)(nbase >> 6) * 8192;
  unsigned short* h1 = (unsigned short*)hbuf + (size_t)(2 * lpair + 1) * kHbufTile +
                       (size_t)(nbase >> 6) * 8192;
#pragma unroll
  for (int i = 0; i < 8; ++i) {
    int s = i * 4096 + tid8;
    *(short8*)(h0 + s) = *(const short8*)&lds[s];
    *(short8*)(h1 + s) = *(const short8*)&lds[32768 + s];
  }
}

// ---------------- GEMM2: proven 128x128 2-phase; out = (h @ W2[e] + b2) * score ------------
__global__ __launch_bounds__(256, 2)
void k_ffn2(const __hip_bfloat16* __restrict__ hbuf,
            const __hip_bfloat16* __restrict__ w2t,  // [E][H][F] bf16
            const __hip_bfloat16* __restrict__ b2,
            const float* __restrict__ wsel,
            const int* __restrict__ tileExpert,
            const int* __restrict__ tileBatch,
            const int* __restrict__ numTiles,
            int tileOff, int chunk,
            float* __restrict__ out) {
  int j = blockIdx.y;
  int local = blockIdx.x + 8 * (j / 6);
  if (local >= chunk) return;
  int tile = local + tileOff;
  if (tile >= *numTiles) return;
  int nbase = (j % 6) * 128;
  int e = tileExpert[tile];
  int tbraw[4];
  float sc[4];
#pragma unroll
  for (int s = 0; s < 4; ++s) {
    int bb = tileBatch[tile * 4 + s];
    tbraw[s] = bb;
    sc[s] = (bb >= 0) ? wsel[bb] : 0.f;
  }
  __shared__ __align__(16) short ldsA[8192];
  __shared__ __align__(16) short ldsB[8192];
  int tid = threadIdx.x;
  int lane = tid & 63, wid = tid >> 6;
  int wm = wid >> 1, wn = wid & 1;
  int lane16 = lane & 15, qf = lane >> 4;
  int swzl = (lane16 >> 1) & 3;
  int qx = (qf ^ swzl) * 8;

  f32x4 acc[4][4];
#pragma unroll
  for (int r = 0; r < 4; ++r)
#pragma unroll
    for (int c = 0; c < 4; ++c) acc[r][c] = (f32x4)0.f;

  const __hip_bfloat16* w2e = w2t + (size_t)e * kF * kH;
  const __hip_bfloat16* htile = hbuf + (size_t)local * kHbufTile;
  const __hip_bfloat16* gB[4];
  short* lA[4];
  short* lB[4];
  int aoff[4];
#pragma unroll
  for (int it = 0; it < 4; ++it) {
    int s = it * 256 + tid;
    int m = (s >> 2) & 127, kk = s >> 9;
    int qq = (s & 3) ^ ((s >> 3) & 3);
    aoff[it] = s * 8;
    gB[it] = w2e + (size_t)(nbase + m) * kF + kk * 32 + qq * 8;
    lA[it] = &ldsA[s * 8];
    lB[it] = &ldsB[s * 8];
  }

  for (int k0 = 0; k0 < kF; k0 += 64) {
#pragma unroll
    for (int it = 0; it < 4; ++it) gld_lds16(htile + k0 * 128 + aoff[it], lA[it]);
#pragma unroll
    for (int it = 0; it < 4; ++it) gld_lds16(gB[it] + k0, lB[it]);
    __syncthreads();
#pragma unroll
    for (int kk = 0; kk < 2; ++kk) {
      short8 af[4], bfr[4];
#pragma unroll
      for (int r = 0; r < 4; ++r) {
        int mr = wm * 64 + r * 16 + lane16;
        af[r] = *(const short8*)&ldsA[(kk * 512 + mr * 4) * 8 + qx];
      }
#pragma unroll
      for (int c = 0; c < 4; ++c) {
        int mb = wn * 64 + c * 16 + lane16;
        bfr[c] = *(const short8*)&ldsB[(kk * 512 + mb * 4) * 8 + qx];
      }
#pragma unroll
      for (int r = 0; r < 4; ++r)
#pragma unroll
        for (int c = 0; c < 4; ++c)
          acc[r][c] = __builtin_amdgcn_mfma_f32_16x16x32_bf16(af[r], bfr[c], acc[r][c], 0, 0, 0);
    }
    __syncthreads();
  }

  int q4 = qf * 4;
#pragma unroll
  for (int c = 0; c < 4; ++c) {
    int ncol = wn * 64 + c * 16 + lane16;
    float bias = bf2f(b2[e * kH + nbase + ncol]);
#pragma unroll
    for (int r = 0; r < 4; ++r) {
      int s = (wm * 64 + r * 16) >> 5;
      int bb = tbraw[s];
      if (bb < 0) continue;
      float scale = sc[s];
#pragma unroll
      for (int g = 0; g < 4; ++g) {
        int m = wm * 64 + r * 16 + q4 + g;
        float v = (acc[r][c][g] + bias) * scale;
        out[((size_t)(bb * kT + (m & 31))) * kH + nbase + ncol] = v;
      }
    }
  }
}

}  // namespace

extern "C" void kernel_launch(void* const* d_in, const int* in_sizes, int n_in,
                              void* d_out, int out_size, void* d_ws, size_t ws_size,
                              hipStream_t stream) {
  (void)in_sizes; (void)n_in; (void)out_size;
  float* out = (float*)d_out;

  char* ws = (char*)d_ws;
  size_t off = 0;
  auto alloc = [&](size_t bytes) -> char* {
    char* p = ws + off;
    off = (off + bytes + 255) & ~(size_t)255;
    return p;
  };
  int*   cntTk      = (int*)alloc(16);      // cnt[3] + ticket
  float* wsel       = (float*)alloc(kB * 4);
  int*   lists      = (int*)alloc((size_t)kE * kB * 4);
  int*   tileExpert = (int*)alloc(kMaxTiles * 4);
  int*   tileBatch  = (int*)alloc(kMaxTiles * 4 * 4);
  int*   numTiles   = (int*)alloc(4);
  __hip_bfloat16* w1t   = (__hip_bfloat16*)alloc((size_t)kE * kH * kF * 2);      // 14.2 MB
  __hip_bfloat16* w2t   = (__hip_bfloat16*)alloc((size_t)kE * kH * kF * 2);      // 14.2 MB
  __hip_bfloat16* xconv = (__hip_bfloat16*)alloc((size_t)kB * kXconvB * 2);      // 25.2 MB

  // adaptive hbuf chunk (deterministic in ws_size); EVEN (pair granularity)
  size_t tileBytes = (size_t)kHbufTile * 2;  // 786432
  size_t avail = (ws_size > off + 2 * tileBytes) ? (ws_size - off) : 2 * tileBytes;
  int chunk = (int)(avail / tileBytes);
  if (chunk > kMaxChunk) chunk = kMaxChunk;
  chunk &= ~1;
  if (chunk < 2) chunk = 2;
  __hip_bfloat16* hbuf = (__hip_bfloat16*)alloc((size_t)chunk * tileBytes);

  hipFuncSetAttribute((const void*)k_ffn1,
                      hipFuncAttributeMaxDynamicSharedMemorySize, 131072);

  hipMemsetAsync(cntTk, 0, 16, stream);
  k_prep<<<kB + 3456, 256, 0, stream>>>(d_in[0], d_in[1], d_in[2], d_in[4],
                                        wsel, cntTk, lists, tileExpert, tileBatch,
                                        numTiles, xconv, w1t, w2t);
  for (int toff = 0; toff < kMaxTiles; toff += chunk) {
    int nblk1 = (chunk / 2) * 12;
    k_ffn1<<<dim3(8, (nblk1 + 7) / 8), 512, 131072, stream>>>(
        xconv, w1t, (const __hip_bfloat16*)d_in[3],
        tileExpert, tileBatch, numTiles, toff, chunk, hbuf);
    int rows2 = (chunk + 7) / 8;
    k_ffn2<<<dim3(8, 6 * rows2), 256, 0, stream>>>(hbuf, w2t,
                                                   (const __hip_bfloat16*)d_in[5], wsel,
                                                   tileExpert, tileBatch, numTiles,
                                                   toff, chunk, out);
  }
}

// Round 8
// 419.951 us; speedup vs baseline: 1.0092x; 1.0092x over previous
//
#include <hip/hip_runtime.h>
#include <hip/hip_bf16.h>
#include <cstdint>
#include <cstddef>

namespace {

constexpr int kB = 512, kT = 32, kH = 768, kF = 3072, kE = 3;
constexpr int kMaxTiles = 132;   // sum 2*ceil(cnt_e/8) <= 132 (pairs, expert-uniform)
constexpr int kMaxChunk = 132;
constexpr int kHbufTile = 128 * kF;   // 393216 elts per 128-row tile
constexpr int kXconvB = kT * kH;      // 24576 elts per batch

typedef __attribute__((ext_vector_type(8))) short short8;
typedef __attribute__((ext_vector_type(4))) float f32x4;

__device__ __forceinline__ void gld_lds16(const void* g, void* l) {
  __builtin_amdgcn_global_load_lds(
      (const __attribute__((address_space(1))) void*)g,
      (__attribute__((address_space(3))) void*)l, 16, 0, 0);
}

__device__ __forceinline__ float bf2f(__hip_bfloat16 v) { return __bfloat162float(v); }
__device__ __forceinline__ float bfu(unsigned short u) {
  return __uint_as_float(((unsigned)u) << 16);
}
__device__ __forceinline__ unsigned short f2bfb(float f) {
  __hip_bfloat16 h = __float2bfloat16(f);
  return *reinterpret_cast<unsigned short*>(&h);
}

// exact-grade gelu: Abramowitz-Stegun 7.1.26 erf, |err| <= 1.5e-7
__device__ __forceinline__ float gelu_f(float v) {
  float av = fabsf(v);
  float z = av * 0.70710678118654752f;
  float t = __builtin_amdgcn_rcpf(fmaf(0.3275911f, z, 1.0f));
  float p = fmaf(fmaf(fmaf(fmaf(1.061405429f, t, -1.453152027f), t, 1.421413741f),
                      t, -0.284496736f), t, 0.254829592f) * t;
  float er = fmaf(-p, __expf(-z * z), 1.0f);   // erf(z), z >= 0
  return 0.5f * v + 0.5f * av * er;
}

// ---------------- merged prep: [0,kB) route+convert blocks; [kB,kB+3456) transpose blocks ----
__global__ __launch_bounds__(256)
void k_prep(const void* __restrict__ xv, const void* __restrict__ Wgv,
            const void* __restrict__ w1src, const void* __restrict__ w2src,
            float* __restrict__ wsel, int* __restrict__ cntTk,
            int* __restrict__ lists, int* __restrict__ tileExpert,
            int* __restrict__ tileBatch, int* __restrict__ numTiles,
            __hip_bfloat16* __restrict__ xconv,
            __hip_bfloat16* __restrict__ w1dst, __hip_bfloat16* __restrict__ w2dst) {
  __shared__ __align__(16) char smem[52992];
  __shared__ int ish[6];
  int tid = threadIdx.x;
  if (blockIdx.x < (unsigned)kB) {
    // ---------------- prep path ----------------
    auto xs = (unsigned short (*)[772])smem;                 // 32 x 772 ushort
    float (*red)[256] = (float (*)[256])(smem + 49408);      // 3 x 256 f32
    int b = blockIdx.x;
    if (tid == 0) { ish[0] = 0; ish[1] = 0; }
    __syncthreads();
    {
      const unsigned short* xw = (const unsigned short*)xv;
      const unsigned short* gw = (const unsigned short*)Wgv;
      int lx = 0, lg = 0;
#pragma unroll
      for (int i = 0; i < 16; ++i) lx += (((xw[tid + 256 * i] >> 7) & 0xFF) >= 0xC0);
#pragma unroll
      for (int i = 0; i < 8; ++i) lg += (((gw[tid + 256 * i] >> 7) & 0xFF) >= 0xC0);
      atomicAdd(&ish[0], lx);
      atomicAdd(&ish[1], lg);
    }
    __syncthreads();
    bool fx = (ish[0] > 64), fg = (ish[1] > 32);
    float a0 = 0.f, a1 = 0.f, a2 = 0.f;
    if (tid < 192) {
      float m0 = 0.f, m1 = 0.f, m2 = 0.f, m3 = 0.f;
      if (fx) {
        const float4* xr = (const float4*)((const float*)xv + (size_t)b * kT * kH) + tid;
#pragma unroll 8
        for (int t = 0; t < kT; ++t) {
          float4 u = xr[t * 192];
          m0 += u.x; m1 += u.y; m2 += u.z; m3 += u.w;
          ushort4 v;
          v.x = f2bfb(u.x); v.y = f2bfb(u.y); v.z = f2bfb(u.z); v.w = f2bfb(u.w);
          *(ushort4*)&xs[t][tid * 4] = v;
        }
      } else {
        const ushort4* xr = (const ushort4*)((const unsigned short*)xv + (size_t)b * kT * kH) + tid;
#pragma unroll 8
        for (int t = 0; t < kT; ++t) {
          ushort4 u = xr[t * 192];
          m0 += bfu(u.x); m1 += bfu(u.y); m2 += bfu(u.z); m3 += bfu(u.w);
          *(ushort4*)&xs[t][tid * 4] = u;
        }
      }
      const float inv = 1.f / kT;
      m0 *= inv; m1 *= inv; m2 *= inv; m3 *= inv;
#pragma unroll
      for (int e = 0; e < kE; ++e) {
        float w0, w1v, w2v, w3;
        int base = e * kH + tid * 4;
        if (fg) {
          float4 u = *(const float4*)((const float*)Wgv + base);
          w0 = u.x; w1v = u.y; w2v = u.z; w3 = u.w;
        } else {
          ushort4 u = *(const ushort4*)((const unsigned short*)Wgv + base);
          w0 = bfu(u.x); w1v = bfu(u.y); w2v = bfu(u.z); w3 = bfu(u.w);
        }
        float d = m0 * w0 + m1 * w1v + m2 * w2v + m3 * w3;
        if (e == 0) a0 = d; else if (e == 1) a1 = d; else a2 = d;
      }
    }
    red[0][tid] = a0; red[1][tid] = a1; red[2][tid] = a2;
    __syncthreads();
    for (int s2 = 128; s2 > 0; s2 >>= 1) {
      if (tid < s2) {
        red[0][tid] += red[0][tid + s2];
        red[1][tid] += red[1][tid + s2];
        red[2][tid] += red[2][tid + s2];
      }
      __syncthreads();
    }
    if (tid == 0) {
      float l0 = red[0][0], l1 = red[1][0], l2 = red[2][0];
      int am = 0; float mx = l0;
      if (l1 > mx) { mx = l1; am = 1; }
      if (l2 > mx) { mx = l2; am = 2; }
      float e0 = expf(l0 - mx), e1 = expf(l1 - mx), e2 = expf(l2 - mx);
      float inv = 1.f / (e0 + e1 + e2);
      float sc = (am == 0 ? e0 : (am == 1 ? e1 : e2)) * inv;
      wsel[b] = sc;
      int pos = atomicAdd(&cntTk[am], 1);
      lists[am * kB + pos] = b;
      __threadfence();                       // release
      int tk = atomicAdd(&cntTk[3], 1);
      ish[2] = (tk == kB - 1) ? 1 : 0;
    }
    __syncthreads();
    // repack xs -> xconv[b] (ffn1 A-staging order)
    unsigned short* dst = (unsigned short*)xconv + (size_t)b * kXconvB;
#pragma unroll
    for (int i = 0; i < 12; ++i) {
      int g = i * 256 + tid;               // 0..3071
      int t32 = g >> 7, r = g & 127, mm = r >> 2, qp = r & 3;
      int col = t32 * 32 + (qp ^ ((mm >> 1) & 3)) * 8;
      ushort4 lo = *(const ushort4*)&xs[mm][col];
      ushort4 hi = *(const ushort4*)&xs[mm][col + 4];
      short8 v;
      v[0] = lo.x; v[1] = lo.y; v[2] = lo.z; v[3] = lo.w;
      v[4] = hi.x; v[5] = hi.y; v[6] = hi.z; v[7] = hi.w;
      *(short8*)(dst + g * 8) = v;
    }
    if (ish[2]) {                          // last block: parallel PAIR-uniform packing
      __threadfence();                     // acquire
      if (tid < 3) ish[3 + tid] = cntTk[tid];
      __syncthreads();
      int c0 = ish[3], c1 = ish[4], c2 = ish[5];
      int t0 = ((c0 + 7) & ~7) >> 2;       // 2*ceil(c/8) -> even, pairs expert-uniform
      int t1 = ((c1 + 7) & ~7) >> 2;
      int t2 = ((c2 + 7) & ~7) >> 2;
      int total = t0 + t1 + t2;
      if (tid == 0) *numTiles = total;
      for (int t = tid; t < kMaxTiles; t += 256) {
        int e = 0, base = 0, cc = 0;
        bool pad = false;
        if (t < t0) { e = 0; base = t; cc = c0; }
        else if (t < t0 + t1) { e = 1; base = t - t0; cc = c1; }
        else if (t < total) { e = 2; base = t - t0 - t1; cc = c2; }
        else pad = true;
        if (pad) {
          tileExpert[t] = 0;
          for (int s = 0; s < 4; ++s) tileBatch[t * 4 + s] = -1;
        } else {
          tileExpert[t] = e;
          for (int s = 0; s < 4; ++s) {
            int i = base * 4 + s;
            tileBatch[t * 4 + s] = (i < cc) ? lists[e * kB + i] : -1;
          }
        }
      }
    }
  } else {
    // ---------------- transpose path ----------------
    auto tsh = (unsigned short (*)[73])smem;                 // 64 x 73 ushort
    int bid = blockIdx.x - kB;
    int z = bid / 576, bx = bid - z * 576;
    bool isW1 = (z < 3);
    int e = isW1 ? z : z - 3;
    if (tid == 0) ish[0] = 0;
    __syncthreads();
    {
      const unsigned short* hw = (const unsigned short*)(isW1 ? w1src : w2src);
      int local = 0;
#pragma unroll
      for (int i = 0; i < 16; ++i)
        local += (((hw[tid + 256 * i] >> 7) & 0xFF) >= 0xC0);
      atomicAdd(&ish[0], local);
    }
    __syncthreads();
    bool f32 = (ish[0] > 64);
    const float* sf = (const float*)(isW1 ? w1src : w2src);
    const unsigned short* sb = (const unsigned short*)(isW1 ? w1src : w2src);
    unsigned short* dst = (unsigned short*)(isW1 ? w1dst : w2dst);
    int K = isW1 ? kH : kF, N = isW1 ? kF : kH;
    int ntx = N / 64;
    int n0 = (bx % ntx) * 64, k0 = (bx / ntx) * 64;
    size_t eoff = (size_t)e * K * N;
    int tr = tid >> 4;
    int tc4 = (tid & 15) * 4;
#pragma unroll
    for (int i = 0; i < 4; ++i) {
      int r = tr + 16 * i;
      size_t idx = eoff + (size_t)(k0 + r) * N + n0 + tc4;
      if (f32) {
        float4 u = *(const float4*)(sf + idx);
        tsh[r][tc4] = f2bfb(u.x); tsh[r][tc4 + 1] = f2bfb(u.y);
        tsh[r][tc4 + 2] = f2bfb(u.z); tsh[r][tc4 + 3] = f2bfb(u.w);
      } else {
        ushort4 u = *(const ushort4*)(sb + idx);
        tsh[r][tc4] = u.x; tsh[r][tc4 + 1] = u.y; tsh[r][tc4 + 2] = u.z; tsh[r][tc4 + 3] = u.w;
      }
    }
    __syncthreads();
#pragma unroll
    for (int i = 0; i < 4; ++i) {
      int rn = tr + 16 * i;
      ushort4 v;
      v.x = tsh[tc4][rn]; v.y = tsh[tc4 + 1][rn];
      v.z = tsh[tc4 + 2][rn]; v.w = tsh[tc4 + 3][rn];
      *(ushort4*)(dst + eoff + (size_t)(n0 + rn) * K + k0 + tc4) = v;
    }
  }
}

// ---------------- GEMM1: 256x256 pair-tile, BK=64, 4 fine phases/K-tile ----------------
// A/B: r7 structure; fence fix: NO lgkmcnt(0)/sched_barrier(0) (m141 failure mode) —
// compiler emits progressive lgkmcnt for its own ds_reads; barriers carry a compiler
// memory fence only (no hardware drain). Counted vmcnt waits unchanged.
__global__ __launch_bounds__(512, 2)
void k_ffn1(const __hip_bfloat16* __restrict__ xconv,
            const __hip_bfloat16* __restrict__ w1t,  // [E][F][H] bf16
            const __hip_bfloat16* __restrict__ b1,
            const int* __restrict__ tileExpert,
            const int* __restrict__ tileBatch,
            const int* __restrict__ numTiles,
            int tileOff, int chunk,
            __hip_bfloat16* __restrict__ hbuf) {
  extern __shared__ __align__(16) short lds[];     // 65536 shorts
  int nblk = (chunk >> 1) * 12;
  int lid = blockIdx.x * gridDim.y + blockIdx.y;   // XCD-chunked
  if (lid >= nblk) return;
  int lpair = lid / 12;
  int nb = lid - lpair * 12;
  int nbase = nb * 256;                            // f-range
  int tile0 = tileOff + 2 * lpair;
  if (tile0 >= *numTiles) return;
  int e = tileExpert[tile0];
  int tid = threadIdx.x;
  int lane = tid & 63, wid = tid >> 6;
  int wr = wid >> 2, wc = wid & 3;                 // 2 row-waves x 4 col-waves
  int lane16 = lane & 15, qf = lane >> 4;
  int qx = (qf ^ ((lane16 >> 1) & 3)) * 8;
  int tid8 = tid * 8;

  // staging sources (per-lane; batches via pair slots 0..7)
  int b0v = tileBatch[tile0 * 4];                  // always valid
  int bA0 = tileBatch[tile0 * 4 + (tid >> 7)];
  int bA1 = tileBatch[tile0 * 4 + 4 + (tid >> 7)];
  if (bA0 < 0) bA0 = b0v;
  if (bA1 < 0) bA1 = b0v;
  int aoffc = (((tid >> 2) & 31) * 4 + (tid & 3)) * 8;
  const __hip_bfloat16* pA0 = xconv + (size_t)bA0 * kXconvB + aoffc;
  const __hip_bfloat16* pA1 = xconv + (size_t)bA1 * kXconvB + aoffc;
  const __hip_bfloat16* w1e = w1t + (size_t)e * kF * kH;
  int q8 = ((tid & 3) ^ ((tid >> 3) & 3)) * 8;
  const __hip_bfloat16* pB0 = w1e + (size_t)(nbase + (tid >> 2)) * kH + q8;
  const __hip_bfloat16* pB1 = w1e + (size_t)(nbase + 128 + (tid >> 2)) * kH + q8;
  const int baseA = (wr * 128 + lane16) * 32 + qx;
  const int baseB = 16384 + (wc * 64 + lane16) * 32 + qx;

  f32x4 acc[8][4];
#pragma unroll
  for (int r = 0; r < 8; ++r)
#pragma unroll
    for (int c = 0; c < 4; ++c) acc[r][c] = (f32x4)0.f;

  // prologue: stage tile 0 chunks in order A-kk0, B-kk0, A-kk1, B-kk1 into slot 0
  gld_lds16(pA0, &lds[tid8]);
  gld_lds16(pA1, &lds[4096 + tid8]);
  gld_lds16(pB0, &lds[16384 + tid8]);
  gld_lds16(pB1, &lds[16384 + 4096 + tid8]);
  gld_lds16(pA0 + 1024, &lds[8192 + tid8]);
  gld_lds16(pA1 + 1024, &lds[8192 + 4096 + tid8]);
  gld_lds16(pB0 + 32, &lds[16384 + 8192 + tid8]);
  gld_lds16(pB1 + 32, &lds[16384 + 8192 + 4096 + tid8]);
  asm volatile("s_waitcnt vmcnt(4)" ::: "memory");   // A-kk0,B-kk0 landed
  asm volatile("s_barrier" ::: "memory");

#define MF(r_, c_, A_, B_) \
  acc[r_][c_] = __builtin_amdgcn_mfma_f32_16x16x32_bf16(A_, B_, acc[r_][c_], 0, 0, 0)
#define MF16(RB)                                                \
  MF(RB + 0, 0, a0, b0); MF(RB + 0, 1, a0, b1);                 \
  MF(RB + 0, 2, a0, b2); MF(RB + 0, 3, a0, b3);                 \
  MF(RB + 1, 0, a1, b0); MF(RB + 1, 1, a1, b1);                 \
  MF(RB + 1, 2, a1, b2); MF(RB + 1, 3, a1, b3);                 \
  MF(RB + 2, 0, a2, b0); MF(RB + 2, 1, a2, b1);                 \
  MF(RB + 2, 2, a2, b2); MF(RB + 2, 3, a2, b3);                 \
  MF(RB + 3, 0, a3, b0); MF(RB + 3, 1, a3, b1);                 \
  MF(RB + 3, 2, a3, b2); MF(RB + 3, 3, a3, b3)
#define BAR asm volatile("s_barrier" ::: "memory")

#pragma unroll 1
  for (int t = 0; t < 12; ++t) {
    const short* cur = &lds[(t & 1) * 32768];
    short* nxt = &lds[((t + 1) & 1) * 32768];
    const bool hn = (t + 1) < 12;
    const int tA = (t + 1) * 2048;
    const int tB = (t + 1) * 64;
    short8 a0, a1, a2, a3, b0, b1, b2, b3;
    // ---- phase 0: kk0, acc rows 0-3; stage A-kk0[t+1]
    b0 = *(const short8*)&cur[baseB];
    b1 = *(const short8*)&cur[baseB + 512];
    b2 = *(const short8*)&cur[baseB + 1024];
    b3 = *(const short8*)&cur[baseB + 1536];
    a0 = *(const short8*)&cur[baseA];
    a1 = *(const short8*)&cur[baseA + 512];
    a2 = *(const short8*)&cur[baseA + 1024];
    a3 = *(const short8*)&cur[baseA + 1536];
    if (hn) {
      gld_lds16(pA0 + tA, nxt + tid8);
      gld_lds16(pA1 + tA, nxt + 4096 + tid8);
    }
    BAR;
    __builtin_amdgcn_s_setprio(1);
    MF16(0);
    __builtin_amdgcn_s_setprio(0);
    BAR;
    // ---- phase 1: kk0, acc rows 4-7; stage B-kk0[t+1]; vmcnt ensures kk1[t] landed
    a0 = *(const short8*)&cur[baseA + 2048];
    a1 = *(const short8*)&cur[baseA + 2560];
    a2 = *(const short8*)&cur[baseA + 3072];
    a3 = *(const short8*)&cur[baseA + 3584];
    if (hn) {
      gld_lds16(pB0 + tB, nxt + 16384 + tid8);
      gld_lds16(pB1 + tB, nxt + 16384 + 4096 + tid8);
      asm volatile("s_waitcnt vmcnt(4)" ::: "memory");
    } else {
      asm volatile("s_waitcnt vmcnt(0)" ::: "memory");
    }
    BAR;
    __builtin_amdgcn_s_setprio(1);
    MF16(4);
    __builtin_amdgcn_s_setprio(0);
    BAR;
    // ---- phase 2: kk1, acc rows 0-3; stage A-kk1[t+1]
    b0 = *(const short8*)&cur[8192 + baseB];
    b1 = *(const short8*)&cur[8192 + baseB + 512];
    b2 = *(const short8*)&cur[8192 + baseB + 1024];
    b3 = *(const short8*)&cur[8192 + baseB + 1536];
    a0 = *(const short8*)&cur[8192 + baseA];
    a1 = *(const short8*)&cur[8192 + baseA + 512];
    a2 = *(const short8*)&cur[8192 + baseA + 1024];
    a3 = *(const short8*)&cur[8192 + baseA + 1536];
    if (hn) {
      gld_lds16(pA0 + tA + 1024, nxt + 8192 + tid8);
      gld_lds16(pA1 + tA + 1024, nxt + 8192 + 4096 + tid8);
    }
    BAR;
    __builtin_amdgcn_s_setprio(1);
    MF16(0);
    __builtin_amdgcn_s_setprio(0);
    BAR;
    // ---- phase 3: kk1, acc rows 4-7; stage B-kk1[t+1]; vmcnt ensures kk0[t+1] landed
    a0 = *(const short8*)&cur[8192 + baseA + 2048];
    a1 = *(const short8*)&cur[8192 + baseA + 2560];
    a2 = *(const short8*)&cur[8192 + baseA + 3072];
    a3 = *(const short8*)&cur[8192 + baseA + 3584];
    if (hn) {
      gld_lds16(pB0 + tB + 32, nxt + 16384 + 8192 + tid8);
      gld_lds16(pB1 + tB + 32, nxt + 16384 + 8192 + 4096 + tid8);
      asm volatile("s_waitcnt vmcnt(4)" ::: "memory");
    }
    BAR;
    __builtin_amdgcn_s_setprio(1);
    MF16(4);
    __builtin_amdgcn_s_setprio(0);
    BAR;
  }
#undef MF
#undef MF16
#undef BAR

  // ---- epilogue: gelu(acc+bias) -> LDS bounce (hbuf-staged order, r5-proven pattern)
  int q4 = qf * 4;
#pragma unroll
  for (int c = 0; c < 4; ++c) {
    int nl = wc * 64 + c * 16 + lane16;            // 0..255 within block f-range
    float bias = bf2f(b1[e * kF + nbase + nl]);
    int lb = wr * 32768 + (nl >> 6) * 8192 + ((nl >> 5) & 1) * 4096 + (nl & 7);
    int qn = (nl >> 3) & 3;
#pragma unroll
    for (int r = 0; r < 8; ++r) {
#pragma unroll
      for (int g = 0; g < 4; ++g) {
        int m = r * 16 + q4 + g;                   // row within 128-row tile
        lds[lb + (m * 4 + (qn ^ ((m >> 1) & 3))) * 8] =
            (short)f2bfb(gelu_f(acc[r][c][g] + bias));
      }
    }
  }
  __syncthreads();
  unsigned short* h0 = (unsigned short*)hbuf + (size_t)(2 * lpair) * kHbufTile +
                       (size_t)(nbase >> 6) * 8192;
  unsigned short* h1 = (unsigned short*)hbuf + (size_t)(2 * lpair + 1) * kHbufTile +
                       (size_t)(nbase >> 6) * 8192;
#pragma unroll
  for (int i = 0; i < 8; ++i) {
    int s = i * 4096 + tid8;
    *(short8*)(h0 + s) = *(const short8*)&lds[s];
    *(short8*)(h1 + s) = *(const short8*)&lds[32768 + s];
  }
}

// ---------------- GEMM2: proven 128x128 2-phase; out = (h @ W2[e] + b2) * score ------------
__global__ __launch_bounds__(256, 2)
void k_ffn2(const __hip_bfloat16* __restrict__ hbuf,
            const __hip_bfloat16* __restrict__ w2t,  // [E][H][F] bf16
            const __hip_bfloat16* __restrict__ b2,
            const float* __restrict__ wsel,
            const int* __restrict__ tileExpert,
            const int* __restrict__ tileBatch,
            const int* __restrict__ numTiles,
            int tileOff, int chunk,
            float* __restrict__ out) {
  int j = blockIdx.y;
  int local = blockIdx.x + 8 * (j / 6);
  if (local >= chunk) return;
  int tile = local + tileOff;
  if (tile >= *numTiles) return;
  int nbase = (j % 6) * 128;
  int e = tileExpert[tile];
  int tbraw[4];
  float sc[4];
#pragma unroll
  for (int s = 0; s < 4; ++s) {
    int bb = tileBatch[tile * 4 + s];
    tbraw[s] = bb;
    sc[s] = (bb >= 0) ? wsel[bb] : 0.f;
  }
  __shared__ __align__(16) short ldsA[8192];
  __shared__ __align__(16) short ldsB[8192];
  int tid = threadIdx.x;
  int lane = tid & 63, wid = tid >> 6;
  int wm = wid >> 1, wn = wid & 1;
  int lane16 = lane & 15, qf = lane >> 4;
  int swzl = (lane16 >> 1) & 3;
  int qx = (qf ^ swzl) * 8;

  f32x4 acc[4][4];
#pragma unroll
  for (int r = 0; r < 4; ++r)
#pragma unroll
    for (int c = 0; c < 4; ++c) acc[r][c] = (f32x4)0.f;

  const __hip_bfloat16* w2e = w2t + (size_t)e * kF * kH;
  const __hip_bfloat16* htile = hbuf + (size_t)local * kHbufTile;
  const __hip_bfloat16* gB[4];
  short* lA[4];
  short* lB[4];
  int aoff[4];
#pragma unroll
  for (int it = 0; it < 4; ++it) {
    int s = it * 256 + tid;
    int m = (s >> 2) & 127, kk = s >> 9;
    int qq = (s & 3) ^ ((s >> 3) & 3);
    aoff[it] = s * 8;
    gB[it] = w2e + (size_t)(nbase + m) * kF + kk * 32 + qq * 8;
    lA[it] = &ldsA[s * 8];
    lB[it] = &ldsB[s * 8];
  }

  for (int k0 = 0; k0 < kF; k0 += 64) {
#pragma unroll
    for (int it = 0; it < 4; ++it) gld_lds16(htile + k0 * 128 + aoff[it], lA[it]);
#pragma unroll
    for (int it = 0; it < 4; ++it) gld_lds16(gB[it] + k0, lB[it]);
    __syncthreads();
#pragma unroll
    for (int kk = 0; kk < 2; ++kk) {
      short8 af[4], bfr[4];
#pragma unroll
      for (int r = 0; r < 4; ++r) {
        int mr = wm * 64 + r * 16 + lane16;
        af[r] = *(const short8*)&ldsA[(kk * 512 + mr * 4) * 8 + qx];
      }
#pragma unroll
      for (int c = 0; c < 4; ++c) {
        int mb = wn * 64 + c * 16 + lane16;
        bfr[c] = *(const short8*)&ldsB[(kk * 512 + mb * 4) * 8 + qx];
      }
#pragma unroll
      for (int r = 0; r < 4; ++r)
#pragma unroll
        for (int c = 0; c < 4; ++c)
          acc[r][c] = __builtin_amdgcn_mfma_f32_16x16x32_bf16(af[r], bfr[c], acc[r][c], 0, 0, 0);
    }
    __syncthreads();
  }

  int q4 = qf * 4;
#pragma unroll
  for (int c = 0; c < 4; ++c) {
    int ncol = wn * 64 + c * 16 + lane16;
    float bias = bf2f(b2[e * kH + nbase + ncol]);
#pragma unroll
    for (int r = 0; r < 4; ++r) {
      int s = (wm * 64 + r * 16) >> 5;
      int bb = tbraw[s];
      if (bb < 0) continue;
      float scale = sc[s];
#pragma unroll
      for (int g = 0; g < 4; ++g) {
        int m = wm * 64 + r * 16 + q4 + g;
        float v = (acc[r][c][g] + bias) * scale;
        out[((size_t)(bb * kT + (m & 31))) * kH + nbase + ncol] = v;
      }
    }
  }
}

}  // namespace

extern "C" void kernel_launch(void* const* d_in, const int* in_sizes, int n_in,
                              void* d_out, int out_size, void* d_ws, size_t ws_size,
                              hipStream_t stream) {
  (void)in_sizes; (void)n_in; (void)out_size;
  float* out = (float*)d_out;

  char* ws = (char*)d_ws;
  size_t off = 0;
  auto alloc = [&](size_t bytes) -> char* {
    char* p = ws + off;
    off = (off + bytes + 255) & ~(size_t)255;
    return p;
  };
  int*   cntTk      = (int*)alloc(16);      // cnt[3] + ticket
  float* wsel       = (float*)alloc(kB * 4);
  int*   lists      = (int*)alloc((size_t)kE * kB * 4);
  int*   tileExpert = (int*)alloc(kMaxTiles * 4);
  int*   tileBatch  = (int*)alloc(kMaxTiles * 4 * 4);
  int*   numTiles   = (int*)alloc(4);
  __hip_bfloat16* w1t   = (__hip_bfloat16*)alloc((size_t)kE * kH * kF * 2);      // 14.2 MB
  __hip_bfloat16* w2t   = (__hip_bfloat16*)alloc((size_t)kE * kH * kF * 2);      // 14.2 MB
  __hip_bfloat16* xconv = (__hip_bfloat16*)alloc((size_t)kB * kXconvB * 2);      // 25.2 MB

  // adaptive hbuf chunk (deterministic in ws_size); EVEN (pair granularity)
  size_t tileBytes = (size_t)kHbufTile * 2;  // 786432
  size_t avail = (ws_size > off + 2 * tileBytes) ? (ws_size - off) : 2 * tileBytes;
  int chunk = (int)(avail / tileBytes);
  if (chunk > kMaxChunk) chunk = kMaxChunk;
  chunk &= ~1;
  if (chunk < 2) chunk = 2;
  __hip_bfloat16* hbuf = (__hip_bfloat16*)alloc((size_t)chunk * tileBytes);

  hipFuncSetAttribute((const void*)k_ffn1,
                      hipFuncAttributeMaxDynamicSharedMemorySize, 131072);

  hipMemsetAsync(cntTk, 0, 16, stream);
  k_prep<<<kB + 3456, 256, 0, stream>>>(d_in[0], d_in[1], d_in[2], d_in[4],
                                        wsel, cntTk, lists, tileExpert, tileBatch,
                                        numTiles, xconv, w1t, w2t);
  for (int toff = 0; toff < kMaxTiles; toff += chunk) {
    int nblk1 = (chunk / 2) * 12;
    k_ffn1<<<dim3(8, (nblk1 + 7) / 8), 512, 131072, stream>>>(
        xconv, w1t, (const __hip_bfloat16*)d_in[3],
        tileExpert, tileBatch, numTiles, toff, chunk, hbuf);
    int rows2 = (chunk + 7) / 8;
    k_ffn2<<<dim3(8, 6 * rows2), 256, 0, stream>>>(hbuf, w2t,
                                                   (const __hip_bfloat16*)d_in[5], wsel,
                                                   tileExpert, tileBatch, numTiles,
                                                   toff, chunk, out);
  }
}

// Round 9
// 381.696 us; speedup vs baseline: 1.1103x; 1.1002x over previous
//
#include <hip/hip_runtime.h>
#include <hip/hip_bf16.h>
#include <cstdint>
#include <cstddef>

namespace {

constexpr int kB = 512, kT = 32, kH = 768, kF = 3072, kE = 3;
constexpr int kMaxTiles = 131;   // sum ceil(cnt_e/4) <= 131
constexpr int kMaxChunk = 131;
constexpr int kXPermTile = 128 * kH;   // 98304 elts per tile
constexpr int kHbufTile  = 128 * kF;   // 393216 elts per tile

typedef __attribute__((ext_vector_type(8))) short short8;
typedef __attribute__((ext_vector_type(4))) float f32x4;

__device__ __forceinline__ void gld_lds16(const void* g, void* l) {
  __builtin_amdgcn_global_load_lds(
      (const __attribute__((address_space(1))) void*)g,
      (__attribute__((address_space(3))) void*)l, 16, 0, 0);
}

__device__ __forceinline__ float bf2f(__hip_bfloat16 v) { return __bfloat162float(v); }
__device__ __forceinline__ float bfu(unsigned short u) {
  return __uint_as_float(((unsigned)u) << 16);
}
__device__ __forceinline__ unsigned short f2bfb(float f) {
  __hip_bfloat16 h = __float2bfloat16(f);
  return *reinterpret_cast<unsigned short*>(&h);
}

// exact-grade gelu: Abramowitz-Stegun 7.1.26 erf, |err| <= 1.5e-7
__device__ __forceinline__ float gelu_f(float v) {
  float av = fabsf(v);
  float z = av * 0.70710678118654752f;
  float t = __builtin_amdgcn_rcpf(fmaf(0.3275911f, z, 1.0f));
  float p = fmaf(fmaf(fmaf(fmaf(1.061405429f, t, -1.453152027f), t, 1.421413741f),
                      t, -0.284496736f), t, 0.254829592f) * t;
  float er = fmaf(-p, __expf(-z * z), 1.0f);   // erf(z), z >= 0
  return 0.5f * v + 0.5f * av * er;
}

// ---- fused per-tensor dtype sniff (4 blocks) + workspace re-init ----
__global__ void k_sniff_all(const unsigned short* __restrict__ x,
                            const unsigned short* __restrict__ g,
                            const unsigned short* __restrict__ w1,
                            const unsigned short* __restrict__ w2,
                            int* __restrict__ flags, int* __restrict__ cnt,
                            int* __restrict__ ticket) {
  int bb = blockIdx.x;
  if (bb == 0 && threadIdx.x < 4) {
    if (threadIdx.x < 3) cnt[threadIdx.x] = 0;
    else *ticket = 0;
  }
  const unsigned short* p = (bb == 0) ? x : (bb == 1) ? g : (bb == 2) ? w1 : w2;
  int nwords = (bb == 1) ? kE * kH : 4096;
  __shared__ int cnt_s;
  if (threadIdx.x == 0) cnt_s = 0;
  __syncthreads();
  int local = 0;
  for (int i = threadIdx.x; i < nwords; i += 256) {
    unsigned e = (p[i] >> 7) & 0xFF;
    if (e >= 0xC0) ++local;
  }
  atomicAdd(&cnt_s, local);
  __syncthreads();
  if (threadIdx.x == 0) flags[bb] = (cnt_s > 64) ? 1 : 0;
}

// ---------------- routing + PARALLEL tile packing in last block ----------------
__global__ void k_route(const void* __restrict__ xv, const void* __restrict__ Wgv,
                        const int* __restrict__ flags,
                        float* __restrict__ wsel,
                        int* __restrict__ cnt, int* __restrict__ lists,
                        int* __restrict__ ticket,
                        int* __restrict__ tileExpert, int* __restrict__ tileBatch,
                        int* __restrict__ numTiles) {
  bool fx = (flags[0] != 0), fg = (flags[1] != 0);
  int b = blockIdx.x;
  int tid = threadIdx.x;
  float a0 = 0.f, a1 = 0.f, a2 = 0.f;
  if (tid < 192) {   // 192 * float4 = 768 h
    float m0 = 0.f, m1 = 0.f, m2 = 0.f, m3 = 0.f;
    if (fx) {
      const float4* xr = (const float4*)((const float*)xv + (size_t)b * kT * kH) + tid;
#pragma unroll 8
      for (int t = 0; t < kT; ++t) {
        float4 u = xr[t * 192];
        m0 += u.x; m1 += u.y; m2 += u.z; m3 += u.w;
      }
    } else {
      const ushort4* xr = (const ushort4*)((const unsigned short*)xv + (size_t)b * kT * kH) + tid;
#pragma unroll 8
      for (int t = 0; t < kT; ++t) {
        ushort4 u = xr[t * 192];
        m0 += bfu(u.x); m1 += bfu(u.y); m2 += bfu(u.z); m3 += bfu(u.w);
      }
    }
    const float inv = 1.f / kT;
    m0 *= inv; m1 *= inv; m2 *= inv; m3 *= inv;
#pragma unroll
    for (int e = 0; e < kE; ++e) {
      float w0, w1v, w2v, w3;
      int base = e * kH + tid * 4;
      if (fg) {
        float4 u = *(const float4*)((const float*)Wgv + base);
        w0 = u.x; w1v = u.y; w2v = u.z; w3 = u.w;
      } else {
        ushort4 u = *(const ushort4*)((const unsigned short*)Wgv + base);
        w0 = bfu(u.x); w1v = bfu(u.y); w2v = bfu(u.z); w3 = bfu(u.w);
      }
      float d = m0 * w0 + m1 * w1v + m2 * w2v + m3 * w3;
      if (e == 0) a0 = d; else if (e == 1) a1 = d; else a2 = d;
    }
  }
  __shared__ float red[3][256];
  __shared__ int lastFlag;
  __shared__ int csh[3];
  red[0][tid] = a0; red[1][tid] = a1; red[2][tid] = a2;
  __syncthreads();
  for (int s2 = 128; s2 > 0; s2 >>= 1) {
    if (tid < s2) {
      red[0][tid] += red[0][tid + s2];
      red[1][tid] += red[1][tid + s2];
      red[2][tid] += red[2][tid + s2];
    }
    __syncthreads();
  }
  if (tid == 0) {
    float l0 = red[0][0], l1 = red[1][0], l2 = red[2][0];
    int am = 0; float mx = l0;
    if (l1 > mx) { mx = l1; am = 1; }
    if (l2 > mx) { mx = l2; am = 2; }
    float e0 = expf(l0 - mx), e1 = expf(l1 - mx), e2 = expf(l2 - mx);
    float inv = 1.f / (e0 + e1 + e2);
    float sc = (am == 0 ? e0 : (am == 1 ? e1 : e2)) * inv;
    wsel[b] = sc;
    int pos = atomicAdd(&cnt[am], 1);
    lists[am * kB + pos] = b;
    __threadfence();                       // publish lists/cnt (release)
    int tk = atomicAdd(ticket, 1);
    lastFlag = (tk == kB - 1) ? 1 : 0;
  }
  __syncthreads();
  if (lastFlag) {                          // last block: ALL threads pack tiles
    __threadfence();                       // acquire
    if (tid < 3) csh[tid] = cnt[tid];
    __syncthreads();
    int c0 = csh[0], c1 = csh[1], c2 = csh[2];
    int t0 = ((c0 + 3) & ~3) >> 2;         // ceil(c/4) tiles per expert
    int t1 = ((c1 + 3) & ~3) >> 2;
    int t2 = ((c2 + 3) & ~3) >> 2;
    int total = t0 + t1 + t2;
    if (tid == 0) *numTiles = total;
    for (int t = tid; t < kMaxTiles; t += 256) {
      int e = 0, base = 0, cc = 0;
      bool pad = false;
      if (t < t0) { e = 0; base = t; cc = c0; }
      else if (t < t0 + t1) { e = 1; base = t - t0; cc = c1; }
      else if (t < total) { e = 2; base = t - t0 - t1; cc = c2; }
      else pad = true;
      if (pad) {
        tileExpert[t] = 0;
        for (int s = 0; s < 4; ++s) tileBatch[t * 4 + s] = -1;
      } else {
        tileExpert[t] = e;
        for (int s = 0; s < 4; ++s) {
          int i = base * 4 + s;
          tileBatch[t * 4 + s] = (i < cc) ? lists[e * kB + i] : -1;
        }
      }
    }
  }
}

// ---------------- fused transpose + convert: both weight tensors, one launch ----------------
// z<3: W1 [e][H][F] -> w1t [e][F][H]; z>=3: W2 [e][F][H] -> w2t [e][H][F]
__global__ __launch_bounds__(256)
void k_transpose6(const void* __restrict__ w1src, const void* __restrict__ w2src,
                  __hip_bfloat16* __restrict__ w1dst, __hip_bfloat16* __restrict__ w2dst,
                  const int* __restrict__ flags) {
  int z = blockIdx.z;
  bool isW1 = (z < 3);
  int e = isW1 ? z : z - 3;
  bool f32 = (flags[isW1 ? 2 : 3] != 0);
  const float* sf = (const float*)(isW1 ? w1src : w2src);
  const unsigned short* sb = (const unsigned short*)(isW1 ? w1src : w2src);
  unsigned short* dst = (unsigned short*)(isW1 ? w1dst : w2dst);
  int K = isW1 ? kH : kF, N = isW1 ? kF : kH;
  int ntx = N / 64;
  int bx = blockIdx.x;
  int n0 = (bx % ntx) * 64, k0 = (bx / ntx) * 64;
  __shared__ __align__(16) unsigned short t[64][73];
  size_t eoff = (size_t)e * K * N;
  int tr = threadIdx.x >> 4;
  int tc4 = (threadIdx.x & 15) * 4;
#pragma unroll
  for (int i = 0; i < 4; ++i) {
    int r = tr + 16 * i;
    size_t idx = eoff + (size_t)(k0 + r) * N + n0 + tc4;
    if (f32) {
      float4 u = *(const float4*)(sf + idx);
      t[r][tc4] = f2bfb(u.x); t[r][tc4 + 1] = f2bfb(u.y);
      t[r][tc4 + 2] = f2bfb(u.z); t[r][tc4 + 3] = f2bfb(u.w);
    } else {
      ushort4 u = *(const ushort4*)(sb + idx);
      t[r][tc4] = u.x; t[r][tc4 + 1] = u.y; t[r][tc4 + 2] = u.z; t[r][tc4 + 3] = u.w;
    }
  }
  __syncthreads();
#pragma unroll
  for (int i = 0; i < 4; ++i) {
    int rn = tr + 16 * i;
    ushort4 v;
    v.x = t[tc4][rn]; v.y = t[tc4 + 1][rn]; v.z = t[tc4 + 2][rn]; v.w = t[tc4 + 3][rn];
    *(ushort4*)(dst + eoff + (size_t)(n0 + rn) * K + k0 + tc4) = v;
  }
}

// ---------------- convert + permute x into ffn1 A-staging order (tile-gathered) ----------------
// xperm[tile][kblk(12)][slot(1024)*8], slot = kk*512 + m*4 + (q ^ ((m>>1)&3))
__global__ __launch_bounds__(256)
void k_convert_x(const void* __restrict__ xv, const int* __restrict__ flags,
                 const int* __restrict__ tileBatch, const int* __restrict__ numTiles,
                 __hip_bfloat16* __restrict__ xperm) {
  int tile = blockIdx.y;
  if (tile >= *numTiles) return;
  int kblk = blockIdx.x;
  bool fx = (flags[0] != 0);
  const float* xf = (const float*)xv;
  const __hip_bfloat16* xb = (const __hip_bfloat16*)xv;
  int tb0 = tileBatch[tile * 4];
  if (tb0 < 0) tb0 = 0;
  int tb[4];
#pragma unroll
  for (int s = 0; s < 4; ++s) {
    int bb = tileBatch[tile * 4 + s];
    tb[s] = (bb < 0) ? tb0 : bb;
  }
  int tid = threadIdx.x;
  short8* dst = (short8*)(xperm + (size_t)tile * kXPermTile + kblk * 8192);
#pragma unroll
  for (int i = 0; i < 4; ++i) {
    int s = i * 256 + tid;
    int m = (s >> 2) & 127, kk = s >> 9;
    int q = (s & 3) ^ ((s >> 3) & 3);   // (m>>1)&3 == (s>>3)&3
    int row = tb[m >> 5] * kT + (m & 31);
    size_t src = (size_t)row * kH + kblk * 64 + kk * 32 + q * 8;
    short8 v;
    if (fx) {
      float4 u = *(const float4*)(xf + src);
      float4 w = *(const float4*)(xf + src + 4);
      v[0] = f2bfb(u.x); v[1] = f2bfb(u.y); v[2] = f2bfb(u.z); v[3] = f2bfb(u.w);
      v[4] = f2bfb(w.x); v[5] = f2bfb(w.y); v[6] = f2bfb(w.z); v[7] = f2bfb(w.w);
    } else {
      v = *(const short8*)(xb + src);
    }
    dst[s] = v;
  }
}

// ---------------- GEMM1: h = gelu(x @ W1[e] + b1), hbuf in ffn2-A-staging order ----------------
// launch_bounds(256,4): target 4 blocks/CU co-residency to hide the 2-phase barrier drains.
__global__ __launch_bounds__(256, 4)
void k_ffn1(const __hip_bfloat16* __restrict__ xperm,
            const __hip_bfloat16* __restrict__ w1t,  // [E][F][H] bf16
            const __hip_bfloat16* __restrict__ b1,
            const int* __restrict__ tileExpert,
            const int* __restrict__ numTiles,
            int tileOff,
            __hip_bfloat16* __restrict__ hbuf) {
  int j = blockIdx.y;
  int local = j / 3;
  int tile = local + tileOff;
  if (tile >= *numTiles) return;
  int nIdx = 8 * (j % 3) + blockIdx.x;
  int nbase = nIdx * 128;
  int e = tileExpert[tile];
  __shared__ __align__(16) short ldsbuf[16384];   // A: [0,8192) B: [8192,16384)
  short* ldsA = ldsbuf;
  short* ldsB = ldsbuf + 8192;
  int tid = threadIdx.x;
  int lane = tid & 63, wid = tid >> 6;
  int wm = wid >> 1, wn = wid & 1;
  int lane16 = lane & 15, qf = lane >> 4;
  int swzl = (lane16 >> 1) & 3;
  int qx = (qf ^ swzl) * 8;

  f32x4 acc[4][4];
#pragma unroll
  for (int r = 0; r < 4; ++r)
#pragma unroll
    for (int c = 0; c < 4; ++c) acc[r][c] = (f32x4)0.f;

  const __hip_bfloat16* w1e = w1t + (size_t)e * kF * kH;
  const __hip_bfloat16* xtile = xperm + (size_t)tile * kXPermTile;
  const __hip_bfloat16* gB[4];
  short* lA[4];
  short* lB[4];
  int aoff[4];
#pragma unroll
  for (int it = 0; it < 4; ++it) {
    int s = it * 256 + tid;
    int m = (s >> 2) & 127, kk = s >> 9;
    int q = (s & 3) ^ ((s >> 3) & 3);
    aoff[it] = s * 8;
    gB[it] = w1e + (size_t)(nbase + m) * kH + kk * 32 + q * 8;
    lA[it] = &ldsA[s * 8];
    lB[it] = &ldsB[s * 8];
  }

  for (int k0 = 0; k0 < kH; k0 += 64) {
#pragma unroll
    for (int it = 0; it < 4; ++it) gld_lds16(xtile + k0 * 128 + aoff[it], lA[it]);
#pragma unroll
    for (int it = 0; it < 4; ++it) gld_lds16(gB[it] + k0, lB[it]);
    __syncthreads();
#pragma unroll
    for (int kk = 0; kk < 2; ++kk) {
      short8 af[4], bfr[4];
#pragma unroll
      for (int r = 0; r < 4; ++r) {
        int mr = wm * 64 + r * 16 + lane16;
        af[r] = *(const short8*)&ldsA[(kk * 512 + mr * 4) * 8 + qx];
      }
#pragma unroll
      for (int c = 0; c < 4; ++c) {
        int mb = wn * 64 + c * 16 + lane16;
        bfr[c] = *(const short8*)&ldsB[(kk * 512 + mb * 4) * 8 + qx];
      }
#pragma unroll
      for (int r = 0; r < 4; ++r)
#pragma unroll
        for (int c = 0; c < 4; ++c)
          acc[r][c] = __builtin_amdgcn_mfma_f32_16x16x32_bf16(af[r], bfr[c], acc[r][c], 0, 0, 0);
    }
    __syncthreads();
  }

  // epilogue: gelu(acc+bias) -> LDS in hbuf-staged order -> contiguous 16B global stores
  __hip_bfloat16* htile = hbuf + (size_t)local * kHbufTile;
  unsigned short* uls = (unsigned short*)ldsbuf;
  int q4 = qf * 4;
#pragma unroll
  for (int c = 0; c < 4; ++c) {
    int nn = wn * 64 + c * 16 + lane16;           // n - nbase in [0,128)
    float bias = bf2f(b1[e * kF + nbase + nn]);
    int lbase = (nn >> 6) * 8192 + ((nn >> 5) & 1) * 4096 + (nn & 7);
    int qn = (nn >> 3) & 3;
#pragma unroll
    for (int r = 0; r < 4; ++r) {
#pragma unroll
      for (int g = 0; g < 4; ++g) {
        int m = wm * 64 + r * 16 + q4 + g;
        float v = acc[r][c][g] + bias;
        uls[lbase + (m * 4 + (qn ^ ((m >> 1) & 3))) * 8] = f2bfb(gelu_f(v));
      }
    }
  }
  __syncthreads();
  unsigned short* dstg = (unsigned short*)htile + (size_t)(nbase >> 6) * 8192;
#pragma unroll
  for (int i = 0; i < 8; ++i) {
    int s = i * 2048 + tid * 8;
    *(short8*)(dstg + s) = *(const short8*)(uls + s);
  }
}

// ---------------- GEMM2: out = (h @ W2[e] + b2) * score, f32 scatter ----------------
__global__ __launch_bounds__(256, 4)
void k_ffn2(const __hip_bfloat16* __restrict__ hbuf,
            const __hip_bfloat16* __restrict__ w2t,  // [E][H][F] bf16
            const __hip_bfloat16* __restrict__ b2,
            const float* __restrict__ wsel,
            const int* __restrict__ tileExpert,
            const int* __restrict__ tileBatch,
            const int* __restrict__ numTiles,
            int tileOff, int chunk,
            float* __restrict__ out) {
  int j = blockIdx.y;
  int local = blockIdx.x + 8 * (j / 6);
  if (local >= chunk) return;
  int tile = local + tileOff;
  if (tile >= *numTiles) return;
  int nbase = (j % 6) * 128;
  int e = tileExpert[tile];
  int tbraw[4];
  float sc[4];
#pragma unroll
  for (int s = 0; s < 4; ++s) {
    int bb = tileBatch[tile * 4 + s];
    tbraw[s] = bb;
    sc[s] = (bb >= 0) ? wsel[bb] : 0.f;
  }
  __shared__ __align__(16) short ldsA[8192];
  __shared__ __align__(16) short ldsB[8192];
  int tid = threadIdx.x;
  int lane = tid & 63, wid = tid >> 6;
  int wm = wid >> 1, wn = wid & 1;
  int lane16 = lane & 15, qf = lane >> 4;
  int swzl = (lane16 >> 1) & 3;
  int qx = (qf ^ swzl) * 8;

  f32x4 acc[4][4];
#pragma unroll
  for (int r = 0; r < 4; ++r)
#pragma unroll
    for (int c = 0; c < 4; ++c) acc[r][c] = (f32x4)0.f;

  const __hip_bfloat16* w2e = w2t + (size_t)e * kF * kH;
  const __hip_bfloat16* htile = hbuf + (size_t)local * kHbufTile;
  const __hip_bfloat16* gB[4];
  short* lA[4];
  short* lB[4];
  int aoff[4];
#pragma unroll
  for (int it = 0; it < 4; ++it) {
    int s = it * 256 + tid;
    int m = (s >> 2) & 127, kk = s >> 9;
    int q = (s & 3) ^ ((s >> 3) & 3);
    aoff[it] = s * 8;
    gB[it] = w2e + (size_t)(nbase + m) * kF + kk * 32 + q * 8;
    lA[it] = &ldsA[s * 8];
    lB[it] = &ldsB[s * 8];
  }

  for (int k0 = 0; k0 < kF; k0 += 64) {
#pragma unroll
    for (int it = 0; it < 4; ++it) gld_lds16(htile + k0 * 128 + aoff[it], lA[it]);
#pragma unroll
    for (int it = 0; it < 4; ++it) gld_lds16(gB[it] + k0, lB[it]);
    __syncthreads();
#pragma unroll
    for (int kk = 0; kk < 2; ++kk) {
      short8 af[4], bfr[4];
#pragma unroll
      for (int r = 0; r < 4; ++r) {
        int mr = wm * 64 + r * 16 + lane16;
        af[r] = *(const short8*)&ldsA[(kk * 512 + mr * 4) * 8 + qx];
      }
#pragma unroll
      for (int c = 0; c < 4; ++c) {
        int mb = wn * 64 + c * 16 + lane16;
        bfr[c] = *(const short8*)&ldsB[(kk * 512 + mb * 4) * 8 + qx];
      }
#pragma unroll
      for (int r = 0; r < 4; ++r)
#pragma unroll
        for (int c = 0; c < 4; ++c)
          acc[r][c] = __builtin_amdgcn_mfma_f32_16x16x32_bf16(af[r], bfr[c], acc[r][c], 0, 0, 0);
    }
    __syncthreads();
  }

  int q4 = qf * 4;
#pragma unroll
  for (int c = 0; c < 4; ++c) {
    int ncol = wn * 64 + c * 16 + lane16;
    float bias = bf2f(b2[e * kH + nbase + ncol]);
#pragma unroll
    for (int r = 0; r < 4; ++r) {
      int s = (wm * 64 + r * 16) >> 5;
      int bb = tbraw[s];
      if (bb < 0) continue;
      float scale = sc[s];
#pragma unroll
      for (int g = 0; g < 4; ++g) {
        int m = wm * 64 + r * 16 + q4 + g;
        float v = (acc[r][c][g] + bias) * scale;
        out[((size_t)(bb * kT + (m & 31))) * kH + nbase + ncol] = v;
      }
    }
  }
}

}  // namespace

extern "C" void kernel_launch(void* const* d_in, const int* in_sizes, int n_in,
                              void* d_out, int out_size, void* d_ws, size_t ws_size,
                              hipStream_t stream) {
  (void)in_sizes; (void)n_in; (void)out_size;
  float* out = (float*)d_out;

  char* ws = (char*)d_ws;
  size_t off = 0;
  auto alloc = [&](size_t bytes) -> char* {
    char* p = ws + off;
    off = (off + bytes + 255) & ~(size_t)255;
    return p;
  };
  int*   flags      = (int*)alloc(16);      // x, Wg, W1, W2
  int*   cnt        = (int*)alloc(kE * 4);
  int*   ticket     = (int*)alloc(4);
  float* wsel       = (float*)alloc(kB * 4);
  int*   lists      = (int*)alloc((size_t)kE * kB * 4);
  int*   tileExpert = (int*)alloc(kMaxTiles * 4);
  int*   tileBatch  = (int*)alloc(kMaxTiles * 4 * 4);
  int*   numTiles   = (int*)alloc(4);
  __hip_bfloat16* w1t   = (__hip_bfloat16*)alloc((size_t)kE * kH * kF * 2);      // 14.2 MB
  __hip_bfloat16* w2t   = (__hip_bfloat16*)alloc((size_t)kE * kH * kF * 2);      // 14.2 MB
  __hip_bfloat16* xperm = (__hip_bfloat16*)alloc((size_t)kMaxTiles * kXPermTile * 2);  // 25.8 MB

  // adaptive hbuf chunk (deterministic in ws_size)
  size_t tileBytes = (size_t)kHbufTile * 2;  // 786432
  size_t avail = (ws_size > off + tileBytes) ? (ws_size - off) : tileBytes;
  int chunk = (int)(avail / tileBytes);
  if (chunk > kMaxChunk) chunk = kMaxChunk;
  if (chunk < 1) chunk = 1;
  __hip_bfloat16* hbuf = (__hip_bfloat16*)alloc((size_t)chunk * tileBytes);

  k_sniff_all<<<4, 256, 0, stream>>>((const unsigned short*)d_in[0],
                                     (const unsigned short*)d_in[1],
                                     (const unsigned short*)d_in[2],
                                     (const unsigned short*)d_in[4],
                                     flags, cnt, ticket);
  k_route<<<kB, 256, 0, stream>>>(d_in[0], d_in[1], flags, wsel, cnt, lists,
                                  ticket, tileExpert, tileBatch, numTiles);
  k_convert_x<<<dim3(kH / 64, kMaxTiles), 256, 0, stream>>>(d_in[0], flags, tileBatch,
                                                            numTiles, xperm);
  k_transpose6<<<dim3(576, 1, 6), 256, 0, stream>>>(d_in[2], d_in[4], w1t, w2t, flags);
  for (int toff = 0; toff < kMaxTiles; toff += chunk) {
    k_ffn1<<<dim3(8, 3 * chunk), 256, 0, stream>>>(xperm, w1t,
                                                   (const __hip_bfloat16*)d_in[3],
                                                   tileExpert, numTiles, toff, hbuf);
    int rows2 = (chunk + 7) / 8;
    k_ffn2<<<dim3(8, 6 * rows2), 256, 0, stream>>>(hbuf, w2t,
                                                   (const __hip_bfloat16*)d_in[5], wsel,
                                                   tileExpert, tileBatch, numTiles,
                                                   toff, chunk, out);
  }
}